// Round 3
// baseline (81.090 us; speedup 1.0000x reference)
//
#include <hip/hip_runtime.h>

#define NIN 5
#define POL 55
#define NW 69
#define ROWS_PER_THREAD 8
#define BLOCK 256
#define TILE (BLOCK * ROWS_PER_THREAD)

// Fused kernel, v3 — consecutive-rows decomposition.
//
// v2 post-mortem: eliminating per-row LDS coefficient reads changed nothing
// (78.4 vs 79.1 us) -> v1 was never LDS-bound (compiler had already CSE'd the
// broadcast reads). Roofline for this kernel is ~4.5 us (28 MB @ 6.3 TB/s);
// the ~34 us residual above the 44.5 us poison-fill is either kernel-side
// transaction/latency pathology or harness floor. v3 changes the only axis
// v1/v2 shared: memory transaction structure. Each thread now owns 8
// CONSECUTIVE rows (n % 8 == 0 -> clean fast path):
//   t:   8 scalar loads  -> 2 global_load_dwordx4
//   out: 8 dwordx2 store -> 4 global_store_dwordx4
//   x:   8 dwordx4, per-lane dense (128 B/lane over 8 insts, fully used)
// If dur_us doesn't move, the residual is harness floor -> roofline.
//
// LDS layout (parse phase):
//   w[0..4]   A_j        (degree-1 coefs)
//   w[5..19]  B_{j<=k}   (degree-2, triangular order)
//   w[20..54] C_{j<=k<=l}(degree-3, triangular order)
//   w[55..59] cos coefs  w[60..64] sin coefs
//   w[65]=omegas[0] w[66]=omegas[1] w[67]=filt[0] w[68]=filt[1]

__device__ __forceinline__ float uniform_load(const float* p) {
    int bits = __builtin_amdgcn_readfirstlane(__float_as_int(*p));
    return __int_as_float(bits);
}

__device__ __forceinline__ float eval_row(const float cw[NW], float w0, float w1,
                                          float4 xv, float tv) {
    float v[NIN] = {xv.x, xv.y, xv.z, xv.w, tv};

    // Trig first: long-latency trans-pipe ops overlap the FMA chain below.
    float s = 0.f;
    #pragma unroll
    for (int j = 0; j < NIN; ++j) {
        s = fmaf(cw[55 + j], __cosf(w0 * v[j]), s);
        s = fmaf(cw[60 + j], __sinf(w1 * v[j]), s);
    }

    // s += sum_j v_j * ( A_j + sum_{k>=j} v_k * ( B_jk + sum_{l>=k} C_jkl v_l ) )
    int i2 = 5, i3 = 20;
    #pragma unroll
    for (int j = 0; j < NIN; ++j) {
        float qj = 0.f;
        #pragma unroll
        for (int kk = j; kk < NIN; ++kk) {
            float rr = cw[i2++];
            #pragma unroll
            for (int l = kk; l < NIN; ++l) rr = fmaf(cw[i3++], v[l], rr);
            qj = fmaf(rr, v[kk], qj);
        }
        s = fmaf(v[j], cw[j] + qj, s);
    }
    return s;
}

__global__ __launch_bounds__(BLOCK) void fused_kernel(
    const float4* __restrict__ x,     // N rows of 4 states
    const float* __restrict__ t,      // N time values
    const float* __restrict__ layer,
    const float* __restrict__ omegas,
    const float* __restrict__ ext_filter,
    const int* __restrict__ E,
    float2* __restrict__ out,         // N float2 rows
    int n) {
    __shared__ float w[NW];
    int k = threadIdx.x;
    if (k < POL) {
        int e[NIN];
        int d = 0;
        #pragma unroll
        for (int j = 0; j < NIN; ++j) { e[j] = E[k * NIN + j]; d += e[j]; }
        // expand exponents into sorted variable multiset (size d <= 3)
        int vars[3] = {0, 0, 0};
        int c = 0;
        for (int j = 0; j < NIN; ++j)
            for (int r = 0; r < e[j]; ++r) vars[c++] = j;
        int slot;
        if (d == 1) {
            slot = vars[0];
        } else if (d == 2) {
            int j = vars[0], kk = vars[1];
            slot = 5 + j * NIN - j * (j - 1) / 2 + (kk - j);
        } else {
            const int base3[5] = {0, 15, 25, 31, 34};
            int j = vars[0], kk = vars[1], l = vars[2];
            int m = NIN - j;
            int a = kk - j;
            slot = 20 + base3[j] + a * m - a * (a - 1) / 2 + (l - kk);
        }
        w[slot] = layer[k];
    } else if (k < POL + 10) {
        w[k] = layer[k];              // trig coefficients pass through
    } else if (k == POL + 10) {
        w[65] = omegas[0];
        w[66] = omegas[1];
        w[67] = ext_filter[0];
        w[68] = ext_filter[1];
    }
    __syncthreads();

    // Wave-uniform coefficients -> SGPRs (zero LDS traffic in the hot loop).
    float cw[NW];
    #pragma unroll
    for (int i = 0; i < NW; ++i)
        cw[i] = uniform_load(&w[i]);

    const float w0 = cw[65], w1 = cw[66];
    const float f0 = cw[67], f1 = cw[68];

    const int g = blockIdx.x * BLOCK + threadIdx.x;   // 8-row group index
    const int base_row = g * ROWS_PER_THREAD;
    if (base_row >= n) return;

    if (base_row + ROWS_PER_THREAD <= n) {
        // Fast path: 8 consecutive rows, fully vectorized t-load and out-store.
        const float4* t4 = (const float4*)t;
        float4 tv0 = t4[2 * g];
        float4 tv1 = t4[2 * g + 1];
        float tv[ROWS_PER_THREAD] = {tv0.x, tv0.y, tv0.z, tv0.w,
                                     tv1.x, tv1.y, tv1.z, tv1.w};
        float4 xv[ROWS_PER_THREAD];
        #pragma unroll
        for (int i = 0; i < ROWS_PER_THREAD; ++i)
            xv[i] = x[base_row + i];

        float s[ROWS_PER_THREAD];
        #pragma unroll
        for (int i = 0; i < ROWS_PER_THREAD; ++i)
            s[i] = eval_row(cw, w0, w1, xv[i], tv[i]);

        float4* out4 = (float4*)out;            // 2 rows per float4
        #pragma unroll
        for (int q = 0; q < ROWS_PER_THREAD / 2; ++q)
            out4[4 * g + q] = make_float4(s[2 * q] * f0, s[2 * q] * f1,
                                          s[2 * q + 1] * f0, s[2 * q + 1] * f1);
    } else {
        // Tail (only when n % 8 != 0): scalar per-row path.
        for (int i = 0; i < ROWS_PER_THREAD; ++i) {
            int row = base_row + i;
            if (row < n) {
                float s = eval_row(cw, w0, w1, x[row], t[row]);
                out[row] = make_float2(s * f0, s * f1);
            }
        }
    }
}

extern "C" void kernel_launch(void* const* d_in, const int* in_sizes, int n_in,
                              void* d_out, int out_size, void* d_ws, size_t ws_size,
                              hipStream_t stream) {
    const float* x          = (const float*)d_in[0];
    const float* t          = (const float*)d_in[1];
    const float* layer      = (const float*)d_in[2];
    const float* omegas     = (const float*)d_in[3];
    const float* ext_filter = (const float*)d_in[4];
    const int*   E          = (const int*)d_in[5];

    int n = in_sizes[1];      // N_DATA (t has one element per row)

    fused_kernel<<<(n + TILE - 1) / TILE, BLOCK, 0, stream>>>(
        (const float4*)x, t, layer, omegas, ext_filter, E,
        (float2*)d_out, n);
}

// Round 4
// 78.179 us; speedup vs baseline: 1.0372x; 1.0372x over previous
//
#include <hip/hip_runtime.h>

#define NIN 5
#define POL 55
#define NW 69
#define ROWS_PER_THREAD 4
#define BLOCK 256
#define TILE (BLOCK * ROWS_PER_THREAD)

// Fused kernel, v4 == v2 (revert to best measured variant, 78.4 us).
//
// Session evidence (3 structurally distinct kernels, all 78-81 us):
//   v1 (LDS coefs, strided rows)            79.1 us
//   v2 (SGPR coefs, strided rows)           78.4 us   <- best
//   v3 (SGPR coefs, consecutive rows, x4)   81.1 us
// Top-5 profiled dispatches every round: 268 MB harness re-poison fills at
// ~44.5 us (73-78% HBM peak). Kernel roofline is ~5 us (28 MB @ 6.3 TB/s,
// 1.3M wave VALU insts); its dispatch never rises above the fill floor.
// The timed window is harness-fill-dominated; kernel-side levers are null.
//
// v2 structure: per-instruction coalesced loads/stores (row = base + r*256),
// wave-uniform coefficients pinned in SGPRs via readfirstlane, full-tile
// fast path issuing all 8 loads up front.
//
// LDS layout (parse phase):
//   w[0..4]   A_j        (degree-1 coefs)
//   w[5..19]  B_{j<=k}   (degree-2, triangular order)
//   w[20..54] C_{j<=k<=l}(degree-3, triangular order)
//   w[55..59] cos coefs  w[60..64] sin coefs
//   w[65]=omegas[0] w[66]=omegas[1] w[67]=filt[0] w[68]=filt[1]

__device__ __forceinline__ float uniform_load(const float* p) {
    int bits = __builtin_amdgcn_readfirstlane(__float_as_int(*p));
    return __int_as_float(bits);
}

__device__ __forceinline__ float eval_row(const float cw[NW], float w0, float w1,
                                          float4 xv, float tv) {
    float v[NIN] = {xv.x, xv.y, xv.z, xv.w, tv};

    // Trig first: long-latency trans-pipe ops overlap the FMA chain below.
    float s = 0.f;
    #pragma unroll
    for (int j = 0; j < NIN; ++j) {
        s = fmaf(cw[55 + j], __cosf(w0 * v[j]), s);
        s = fmaf(cw[60 + j], __sinf(w1 * v[j]), s);
    }

    // s += sum_j v_j * ( A_j + sum_{k>=j} v_k * ( B_jk + sum_{l>=k} C_jkl v_l ) )
    int i2 = 5, i3 = 20;
    #pragma unroll
    for (int j = 0; j < NIN; ++j) {
        float qj = 0.f;
        #pragma unroll
        for (int kk = j; kk < NIN; ++kk) {
            float rr = cw[i2++];
            #pragma unroll
            for (int l = kk; l < NIN; ++l) rr = fmaf(cw[i3++], v[l], rr);
            qj = fmaf(rr, v[kk], qj);
        }
        s = fmaf(v[j], cw[j] + qj, s);
    }
    return s;
}

__global__ __launch_bounds__(BLOCK) void fused_kernel(
    const float4* __restrict__ x,     // N rows of 4 states
    const float* __restrict__ t,      // N time values
    const float* __restrict__ layer,
    const float* __restrict__ omegas,
    const float* __restrict__ ext_filter,
    const int* __restrict__ E,
    float2* __restrict__ out,         // N float2 rows
    int n) {
    __shared__ float w[NW];
    int k = threadIdx.x;
    if (k < POL) {
        int e[NIN];
        int d = 0;
        #pragma unroll
        for (int j = 0; j < NIN; ++j) { e[j] = E[k * NIN + j]; d += e[j]; }
        // expand exponents into sorted variable multiset (size d <= 3)
        int vars[3] = {0, 0, 0};
        int c = 0;
        for (int j = 0; j < NIN; ++j)
            for (int r = 0; r < e[j]; ++r) vars[c++] = j;
        int slot;
        if (d == 1) {
            slot = vars[0];
        } else if (d == 2) {
            int j = vars[0], kk = vars[1];
            slot = 5 + j * NIN - j * (j - 1) / 2 + (kk - j);
        } else {
            const int base3[5] = {0, 15, 25, 31, 34};
            int j = vars[0], kk = vars[1], l = vars[2];
            int m = NIN - j;
            int a = kk - j;
            slot = 20 + base3[j] + a * m - a * (a - 1) / 2 + (l - kk);
        }
        w[slot] = layer[k];
    } else if (k < POL + 10) {
        w[k] = layer[k];              // trig coefficients pass through
    } else if (k == POL + 10) {
        w[65] = omegas[0];
        w[66] = omegas[1];
        w[67] = ext_filter[0];
        w[68] = ext_filter[1];
    }
    __syncthreads();

    // Wave-uniform coefficients -> SGPRs (zero LDS traffic in the hot loop).
    float cw[NW];
    #pragma unroll
    for (int i = 0; i < NW; ++i)
        cw[i] = uniform_load(&w[i]);

    const float w0 = cw[65], w1 = cw[66];
    const float f0 = cw[67], f1 = cw[68];

    const int base = blockIdx.x * TILE + threadIdx.x;
    const bool full = (blockIdx.x * TILE + TILE) <= n;   // block-uniform

    if (full) {
        // Fast path: no per-row bounds branch -> all 8 loads issue up front.
        float4 xv[ROWS_PER_THREAD];
        float  tv[ROWS_PER_THREAD];
        #pragma unroll
        for (int r = 0; r < ROWS_PER_THREAD; ++r) {
            xv[r] = x[base + r * BLOCK];
            tv[r] = t[base + r * BLOCK];
        }
        #pragma unroll
        for (int r = 0; r < ROWS_PER_THREAD; ++r) {
            float s = eval_row(cw, w0, w1, xv[r], tv[r]);
            out[base + r * BLOCK] = make_float2(s * f0, s * f1);
        }
    } else {
        #pragma unroll
        for (int r = 0; r < ROWS_PER_THREAD; ++r) {
            int row = base + r * BLOCK;
            if (row < n) {
                float s = eval_row(cw, w0, w1, x[row], t[row]);
                out[row] = make_float2(s * f0, s * f1);
            }
        }
    }
}

extern "C" void kernel_launch(void* const* d_in, const int* in_sizes, int n_in,
                              void* d_out, int out_size, void* d_ws, size_t ws_size,
                              hipStream_t stream) {
    const float* x          = (const float*)d_in[0];
    const float* t          = (const float*)d_in[1];
    const float* layer      = (const float*)d_in[2];
    const float* omegas     = (const float*)d_in[3];
    const float* ext_filter = (const float*)d_in[4];
    const int*   E          = (const int*)d_in[5];

    int n = in_sizes[1];      // N_DATA (t has one element per row)

    fused_kernel<<<(n + TILE - 1) / TILE, BLOCK, 0, stream>>>(
        (const float4*)x, t, layer, omegas, ext_filter, E,
        (float2*)d_out, n);
}